// Round 4
// baseline (500.984 us; speedup 1.0000x reference)
//
#include <hip/hip_runtime.h>

#define NUM_CLASSES 64
#define GRID 2048

typedef float f32x4 __attribute__((ext_vector_type(4)));
typedef int   i32x4 __attribute__((ext_vector_type(4)));

// Single fused kernel: exp column sums + target histogram + NLL pick + final
// combine in the last-arriving block (ticket). 16 lanes per row-quad; each
// thread owns 4 CONSECUTIVE rows (one i32x4 of targets, 4 float4 pred loads).
__global__ __launch_bounds__(256) void loss_fused(
    const float* __restrict__ pred,      // [n][64]
    const int* __restrict__ tgt,         // [n]
    float* __restrict__ g_colsum,        // ws+0    [64] f32 (zeroed)
    unsigned int* __restrict__ g_cnt,    // ws+256  [64] u32 (zeroed)
    float* __restrict__ g_nll,           // ws+512  f32     (zeroed)
    unsigned int* __restrict__ ticket,   // ws+516  u32     (zeroed)
    float* __restrict__ out,             // [1]
    int n)
{
    __shared__ float s_col[NUM_CLASSES];
    __shared__ unsigned int s_cnt[NUM_CLASSES];
    __shared__ float s_nll[4];
    __shared__ int s_last;

    const int t = threadIdx.x;
    if (t < NUM_CLASSES) { s_col[t] = 0.f; s_cnt[t] = 0u; }
    __syncthreads();

    const int c16  = t & 15;      // column quad (owns cols c0..c0+3)
    const int rgrp = t >> 4;      // row quad within block slab
    const int c0   = c16 * 4;

    // balanced row range, row-granular (kills the 15-vs-16-iter quantization)
    const long start = (long)blockIdx.x * n / GRID;
    const long end   = (long)(blockIdx.x + 1) * n / GRID;

    float ca0 = 0.f, ca1 = 0.f, ca2 = 0.f, ca3 = 0.f;
    float nllacc = 0.f;

    long base = start;
    for (; base + 64 <= end; base += 64) {
        const long r0 = base + rgrp * 4;
        const float* p = pred + r0 * NUM_CLASSES + c0;
        // 4 independent 16B loads + one 16B target load in flight
        const f32x4 v0 = __builtin_nontemporal_load((const f32x4*)(p));
        const f32x4 v1 = __builtin_nontemporal_load((const f32x4*)(p + 64));
        const f32x4 v2 = __builtin_nontemporal_load((const f32x4*)(p + 128));
        const f32x4 v3 = __builtin_nontemporal_load((const f32x4*)(p + 192));
        const i32x4 tg = __builtin_nontemporal_load((const i32x4*)(tgt + r0));

        ca0 += __expf(v0[0]); ca1 += __expf(v0[1]); ca2 += __expf(v0[2]); ca3 += __expf(v0[3]);
        ca0 += __expf(v1[0]); ca1 += __expf(v1[1]); ca2 += __expf(v1[2]); ca3 += __expf(v1[3]);
        ca0 += __expf(v2[0]); ca1 += __expf(v2[1]); ca2 += __expf(v2[2]); ca3 += __expf(v2[3]);
        ca0 += __expf(v3[0]); ca1 += __expf(v3[1]); ca2 += __expf(v3[2]); ca3 += __expf(v3[3]);

        // histogram: lanes c16=0..3 each contribute one of this quad's rows
        const int hv = tg[c16 & 3];
        if (c16 < 4) atomicAdd(&s_cnt[hv], 1u);

        // NLL pick: exactly one lane per row owns the target column
        int d;
        d = tg[0] - c0; if ((unsigned)d < 4u) nllacc += (d==0)?v0[0]:(d==1)?v0[1]:(d==2)?v0[2]:v0[3];
        d = tg[1] - c0; if ((unsigned)d < 4u) nllacc += (d==0)?v1[0]:(d==1)?v1[1]:(d==2)?v1[2]:v1[3];
        d = tg[2] - c0; if ((unsigned)d < 4u) nllacc += (d==0)?v2[0]:(d==1)?v2[1]:(d==2)?v2[2]:v2[3];
        d = tg[3] - c0; if ((unsigned)d < 4u) nllacc += (d==0)?v3[0]:(d==1)?v3[1]:(d==2)?v3[2]:v3[3];
    }

    // row-masked tail (≤63 rows), traffic stays balanced to ±1 row
    #pragma unroll
    for (int j = 0; j < 4; ++j) {
        const long row = base + rgrp * 4 + j;
        if (row < end) {
            const f32x4 w = *(const f32x4*)(pred + row * NUM_CLASSES + c0);
            const int g = tgt[row];
            ca0 += __expf(w[0]); ca1 += __expf(w[1]); ca2 += __expf(w[2]); ca3 += __expf(w[3]);
            if (c16 == j) atomicAdd(&s_cnt[g], 1u);
            const int d = g - c0;
            if ((unsigned)d < 4u) nllacc += (d==0)?w[0]:(d==1)?w[1]:(d==2)?w[2]:w[3];
        }
    }

    // block reduction
    atomicAdd(&s_col[c0 + 0], ca0);
    atomicAdd(&s_col[c0 + 1], ca1);
    atomicAdd(&s_col[c0 + 2], ca2);
    atomicAdd(&s_col[c0 + 3], ca3);

    for (int off = 32; off; off >>= 1) nllacc += __shfl_down(nllacc, off);
    if ((t & 63) == 0) s_nll[t >> 6] = nllacc;
    __syncthreads();

    // global accumulation (device-scope atomics -> coherent at L2)
    if (t == 0) atomicAdd(g_nll, s_nll[0] + s_nll[1] + s_nll[2] + s_nll[3]);
    if (t < NUM_CLASSES) {
        atomicAdd(&g_colsum[t], s_col[t]);
        atomicAdd(&g_cnt[t], s_cnt[t]);
    }

    // ticket: last block to finish does the finalize
    __threadfence();
    __syncthreads();
    if (t == 0) {
        const unsigned old = __hip_atomic_fetch_add(ticket, 1u, __ATOMIC_ACQ_REL,
                                                    __HIP_MEMORY_SCOPE_AGENT);
        s_last = (old == GRID - 1u);
    }
    __syncthreads();

    if (s_last && t < NUM_CLASSES) {
        const float    cs  = __hip_atomic_load(&g_colsum[t], __ATOMIC_RELAXED, __HIP_MEMORY_SCOPE_AGENT);
        const unsigned cn  = __hip_atomic_load(&g_cnt[t],    __ATOMIC_RELAXED, __HIP_MEMORY_SCOPE_AGENT);
        const float    nll = __hip_atomic_load(g_nll,        __ATOMIC_RELAXED, __HIP_MEMORY_SCOPE_AGENT);
        const float diff = (float)cn - cs;
        float p = diff * diff;
        for (int off = 32; off; off >>= 1) p += __shfl_down(p, off);
        if (t == 0) out[0] = (p - nll) / (float)n;
    }
}

extern "C" void kernel_launch(void* const* d_in, const int* in_sizes, int n_in,
                              void* d_out, int out_size, void* d_ws, size_t ws_size,
                              hipStream_t stream)
{
    const float* pred = (const float*)d_in[0];
    const int* tgt    = (const int*)d_in[1];
    const int n       = in_sizes[1];

    float*        g_colsum = (float*)d_ws;
    unsigned int* g_cnt    = (unsigned int*)((char*)d_ws + 256);
    float*        g_nll    = (float*)((char*)d_ws + 512);
    unsigned int* ticket   = (unsigned int*)((char*)d_ws + 516);

    (void)hipMemsetAsync(d_ws, 0, 1024, stream);  // zero accumulators + ticket

    loss_fused<<<GRID, 256, 0, stream>>>(pred, tgt, g_colsum, g_cnt, g_nll,
                                         ticket, (float*)d_out, n);
}

// Round 5
// 121.420 us; speedup vs baseline: 4.1260x; 4.1260x over previous
//
#include <hip/hip_runtime.h>

#define NUM_CLASSES 64
#define MAX_GRID 2048

typedef float f32x4 __attribute__((ext_vector_type(4)));

// Pass 1: exp column sums + target histogram + NLL pick, per-block partials.
// 16 lanes per row (lane c16 owns cols 4*c16..4*c16+3); a wave's float4 load
// covers 4 consecutive rows = 1KB contiguous. 4 rows/thread in flight (ILP).
// Balanced row ranges: block b owns rows [b*n/grid, (b+1)*n/grid).
__global__ __launch_bounds__(256) void loss_pass1(
    const float* __restrict__ pred,      // [n][64]
    const int* __restrict__ tgt,         // [n]
    float* __restrict__ part_col,        // [grid][64]
    float* __restrict__ part_cnt,        // [grid][64] (stored as float)
    float* __restrict__ part_nll,        // [grid]
    int n, int grid)
{
    __shared__ float s_col[NUM_CLASSES];
    __shared__ unsigned int s_cnt[NUM_CLASSES];
    __shared__ float s_nll[4];

    const int t = threadIdx.x;
    if (t < NUM_CLASSES) { s_col[t] = 0.f; s_cnt[t] = 0u; }
    __syncthreads();

    const int c16  = t & 15;          // column quad
    const int rloc = t >> 4;          // row within 16-row slab
    const int c0   = c16 * 4;

    const long start = (long)blockIdx.x * n / grid;
    const long end   = (long)(blockIdx.x + 1) * n / grid;

    float ca0 = 0.f, ca1 = 0.f, ca2 = 0.f, ca3 = 0.f;
    float nllacc = 0.f;

    long base = start;
    for (; base + 64 <= end; base += 64) {
        f32x4 v[4];
        int   tg[4];
        #pragma unroll
        for (int j = 0; j < 4; ++j) {   // issue all loads first (ILP)
            const long row = base + rloc + j * 16;
            v[j]  = __builtin_nontemporal_load(
                      reinterpret_cast<const f32x4*>(pred + row * NUM_CLASSES + c0));
            tg[j] = tgt[row];
        }
        #pragma unroll
        for (int j = 0; j < 4; ++j) {
            ca0 += __expf(v[j][0]);
            ca1 += __expf(v[j][1]);
            ca2 += __expf(v[j][2]);
            ca3 += __expf(v[j][3]);
            if (c16 == j) atomicAdd(&s_cnt[tg[j]], 1u);  // 1 atomic per row, spread
            const int d = tg[j] - c0;
            if ((unsigned)d < 4u)
                nllacc += (d==0)?v[j][0]:(d==1)?v[j][1]:(d==2)?v[j][2]:v[j][3];
        }
    }

    // masked tail (< 64 rows)
    #pragma unroll
    for (int j = 0; j < 4; ++j) {
        const long row = base + rloc + j * 16;
        if (row < end) {
            const f32x4 w = *reinterpret_cast<const f32x4*>(pred + row * NUM_CLASSES + c0);
            const int g = tgt[row];
            ca0 += __expf(w[0]); ca1 += __expf(w[1]); ca2 += __expf(w[2]); ca3 += __expf(w[3]);
            if (c16 == j) atomicAdd(&s_cnt[g], 1u);
            const int d = g - c0;
            if ((unsigned)d < 4u) nllacc += (d==0)?w[0]:(d==1)?w[1]:(d==2)?w[2]:w[3];
        }
    }

    // block reduction -> per-block partial slots (no global atomics, no memset)
    atomicAdd(&s_col[c0 + 0], ca0);
    atomicAdd(&s_col[c0 + 1], ca1);
    atomicAdd(&s_col[c0 + 2], ca2);
    atomicAdd(&s_col[c0 + 3], ca3);

    for (int off = 32; off; off >>= 1) nllacc += __shfl_down(nllacc, off);
    if ((t & 63) == 0) s_nll[t >> 6] = nllacc;
    __syncthreads();

    if (t < NUM_CLASSES) {
        part_col[(long)blockIdx.x * NUM_CLASSES + t] = s_col[t];
        part_cnt[(long)blockIdx.x * NUM_CLASSES + t] = (float)s_cnt[t];
    }
    if (t == 0)
        part_nll[blockIdx.x] = s_nll[0] + s_nll[1] + s_nll[2] + s_nll[3];
}

// Finalize: reduce per-block partials -> scalar loss. One block.
__global__ __launch_bounds__(1024) void loss_finalize(
    const float* __restrict__ part_col,
    const float* __restrict__ part_cnt,
    const float* __restrict__ part_nll,
    float* __restrict__ out, int n, int grid)
{
    __shared__ float s_col[NUM_CLASSES];
    __shared__ float s_cnt[NUM_CLASSES];
    __shared__ float s_red[16];

    const int t = threadIdx.x;
    if (t < NUM_CLASSES) { s_col[t] = 0.f; s_cnt[t] = 0.f; }
    __syncthreads();

    const int c   = t & 63;     // class
    const int grp = t >> 6;     // 16 groups over blocks

    float sc = 0.f, sn = 0.f;
    for (int b = grp; b < grid; b += 16) {
        sc += part_col[(long)b * NUM_CLASSES + c];
        sn += part_cnt[(long)b * NUM_CLASSES + c];
    }
    atomicAdd(&s_col[c], sc);
    atomicAdd(&s_cnt[c], sn);

    float np = 0.f;
    for (int b = t; b < grid; b += 1024) np += part_nll[b];
    for (int off = 32; off; off >>= 1) np += __shfl_down(np, off);
    if ((t & 63) == 0) s_red[t >> 6] = np;
    __syncthreads();

    if (t < NUM_CLASSES) {   // exactly wave 0
        const float diff = s_cnt[t] - s_col[t];
        float p = diff * diff;
        for (int off = 32; off; off >>= 1) p += __shfl_down(p, off);
        if (t == 0) {
            float nll = 0.f;
            #pragma unroll
            for (int i = 0; i < 16; ++i) nll += s_red[i];
            out[0] = (p - nll) / (float)n;
        }
    }
}

extern "C" void kernel_launch(void* const* d_in, const int* in_sizes, int n_in,
                              void* d_out, int out_size, void* d_ws, size_t ws_size,
                              hipStream_t stream)
{
    const float* pred = (const float*)d_in[0];
    const int* tgt    = (const int*)d_in[1];
    const int n       = in_sizes[1];

    // ws layout: part_col[grid*64] f32 | part_cnt[grid*64] f32 | part_nll[grid] f32
    // bytes per block = 64*4*2 + 4 = 516. Shrink grid if ws is small (deterministic).
    int grid = MAX_GRID;
    const size_t per_block = (size_t)NUM_CLASSES * 4 * 2 + 4;
    if (ws_size < (size_t)grid * per_block) {
        grid = (int)(ws_size / per_block);
        if (grid < 1) grid = 1;
    }

    float* part_col = (float*)d_ws;
    float* part_cnt = part_col + (size_t)grid * NUM_CLASSES;
    float* part_nll = part_cnt + (size_t)grid * NUM_CLASSES;

    loss_pass1<<<grid, 256, 0, stream>>>(pred, tgt, part_col, part_cnt, part_nll, n, grid);
    loss_finalize<<<1, 1024, 0, stream>>>(part_col, part_cnt, part_nll, (float*)d_out, n, grid);
}

// Round 6
// 109.554 us; speedup vs baseline: 4.5730x; 1.1083x over previous
//
#include <hip/hip_runtime.h>

#define NUM_CLASSES 64
#define GRID 2048

typedef float f32x4 __attribute__((ext_vector_type(4)));
typedef int   i32x4 __attribute__((ext_vector_type(4)));

// Pass 1: exp column sums + target histogram + NLL pick.
// Thread (rgrp, c16) owns 4 CONSECUTIVE rows (one i32x4 of targets) and
// columns 4*c16..4*c16+3. Block-end: LDS reduce -> 66 device atomics.
__global__ __launch_bounds__(256) void loss_pass1(
    const float* __restrict__ pred,      // [n][64]
    const int* __restrict__ tgt,         // [n]
    float* __restrict__ g_colsum,        // [64]  (zeroed by memset)
    unsigned int* __restrict__ g_cnt,    // [64]  (zeroed)
    float* __restrict__ g_nll,           // [1]   (zeroed)
    int n)
{
    __shared__ float s_col[NUM_CLASSES];
    __shared__ unsigned int s_cnt[NUM_CLASSES];
    __shared__ float s_nll[4];

    const int t = threadIdx.x;
    if (t < NUM_CLASSES) { s_col[t] = 0.f; s_cnt[t] = 0u; }
    __syncthreads();

    const int c16  = t & 15;      // column quad (cols c0..c0+3)
    const int rgrp = t >> 4;      // row quad within the block's 64-row slab
    const int c0   = c16 * 4;

    // balanced row ranges, rounded to x4 rows so i32x4 target loads stay aligned
    long start = (long)blockIdx.x * n / GRID & ~3L;
    long end   = (blockIdx.x == GRID - 1) ? n : ((long)(blockIdx.x + 1) * n / GRID & ~3L);

    float ca0 = 0.f, ca1 = 0.f, ca2 = 0.f, ca3 = 0.f;
    float nllacc = 0.f;

    long base = start;
    for (; base + 64 <= end; base += 64) {
        const long r0 = base + rgrp * 4;
        const float* p = pred + r0 * NUM_CLASSES + c0;
        // 4 independent 16B pred loads + one 16B target load in flight
        const f32x4 v0 = __builtin_nontemporal_load((const f32x4*)(p));
        const f32x4 v1 = __builtin_nontemporal_load((const f32x4*)(p + 64));
        const f32x4 v2 = __builtin_nontemporal_load((const f32x4*)(p + 128));
        const f32x4 v3 = __builtin_nontemporal_load((const f32x4*)(p + 192));
        const i32x4 tg = __builtin_nontemporal_load((const i32x4*)(tgt + r0));

        ca0 += __expf(v0[0]); ca1 += __expf(v0[1]); ca2 += __expf(v0[2]); ca3 += __expf(v0[3]);
        ca0 += __expf(v1[0]); ca1 += __expf(v1[1]); ca2 += __expf(v1[2]); ca3 += __expf(v1[3]);
        ca0 += __expf(v2[0]); ca1 += __expf(v2[1]); ca2 += __expf(v2[2]); ca3 += __expf(v2[3]);
        ca0 += __expf(v3[0]); ca1 += __expf(v3[1]); ca2 += __expf(v3[2]); ca3 += __expf(v3[3]);

        // histogram: within each rgrp group, lanes c16=0..3 push rows 0..3
        if (c16 < 4) atomicAdd(&s_cnt[tg[c16]], 1u);

        // NLL pick: exactly one lane per row owns the target column
        int d;
        d = tg[0] - c0; if ((unsigned)d < 4u) nllacc += (d==0)?v0[0]:(d==1)?v0[1]:(d==2)?v0[2]:v0[3];
        d = tg[1] - c0; if ((unsigned)d < 4u) nllacc += (d==0)?v1[0]:(d==1)?v1[1]:(d==2)?v1[2]:v1[3];
        d = tg[2] - c0; if ((unsigned)d < 4u) nllacc += (d==0)?v2[0]:(d==1)?v2[1]:(d==2)?v2[2]:v2[3];
        d = tg[3] - c0; if ((unsigned)d < 4u) nllacc += (d==0)?v3[0]:(d==1)?v3[1]:(d==2)?v3[2]:v3[3];
    }

    // masked tail (< 64 rows)
    #pragma unroll
    for (int j = 0; j < 4; ++j) {
        const long row = base + rgrp * 4 + j;
        if (row < end) {
            const f32x4 w = *(const f32x4*)(pred + row * NUM_CLASSES + c0);
            const int g = tgt[row];
            ca0 += __expf(w[0]); ca1 += __expf(w[1]); ca2 += __expf(w[2]); ca3 += __expf(w[3]);
            if (c16 == j) atomicAdd(&s_cnt[g], 1u);
            const int d = g - c0;
            if ((unsigned)d < 4u) nllacc += (d==0)?w[0]:(d==1)?w[1]:(d==2)?w[2]:w[3];
        }
    }

    // block reduction
    atomicAdd(&s_col[c0 + 0], ca0);
    atomicAdd(&s_col[c0 + 1], ca1);
    atomicAdd(&s_col[c0 + 2], ca2);
    atomicAdd(&s_col[c0 + 3], ca3);

    for (int off = 32; off; off >>= 1) nllacc += __shfl_down(nllacc, off);
    if ((t & 63) == 0) s_nll[t >> 6] = nllacc;
    __syncthreads();

    // device-scope atomic accumulation (66 atomics/block; proven fast in R2)
    if (t == 0) atomicAdd(g_nll, s_nll[0] + s_nll[1] + s_nll[2] + s_nll[3]);
    if (t < NUM_CLASSES) {
        atomicAdd(&g_colsum[t], s_col[t]);
        atomicAdd(&g_cnt[t], s_cnt[t]);
    }
}

// Finalize: 64 threads, reads 516B, writes the scalar.
__global__ void loss_finalize(const float* __restrict__ g_colsum,
                              const unsigned int* __restrict__ g_cnt,
                              const float* __restrict__ g_nll,
                              float* __restrict__ out, int n)
{
    const int t = threadIdx.x;
    const float diff = (float)g_cnt[t] - g_colsum[t];
    float p = diff * diff;
    for (int off = 32; off; off >>= 1) p += __shfl_down(p, off);
    if (t == 0) out[0] = (p - g_nll[0]) / (float)n;
}

extern "C" void kernel_launch(void* const* d_in, const int* in_sizes, int n_in,
                              void* d_out, int out_size, void* d_ws, size_t ws_size,
                              hipStream_t stream)
{
    const float* pred = (const float*)d_in[0];
    const int* tgt    = (const int*)d_in[1];
    const int n       = in_sizes[1];

    float*        g_colsum = (float*)d_ws;
    unsigned int* g_cnt    = (unsigned int*)((char*)d_ws + 256);
    float*        g_nll    = (float*)((char*)d_ws + 512);

    (void)hipMemsetAsync(d_ws, 0, 1024, stream);

    loss_pass1<<<GRID, 256, 0, stream>>>(pred, tgt, g_colsum, g_cnt, g_nll, n);
    loss_finalize<<<1, 64, 0, stream>>>(g_colsum, g_cnt, g_nll, (float*)d_out, n);
}

// Round 7
// 106.141 us; speedup vs baseline: 4.7200x; 1.0322x over previous
//
#include <hip/hip_runtime.h>

#define NUM_CLASSES 64
#define GRID 1250   // n = 2,000,000 = 1250 blocks x 25 slabs x 64 rows exactly

typedef float f32x4 __attribute__((ext_vector_type(4)));

// Pass 1: exp column sums + target histogram + NLL pick (R2-proven hot loop).
// 16 lanes per row (lane c16 owns cols 4*c16..), wave covers 4 consecutive
// rows per load instr = 1KB contiguous. 4 independent row loads in flight.
__global__ __launch_bounds__(256) void loss_pass1(
    const float* __restrict__ pred,      // [n][64]
    const int* __restrict__ tgt,         // [n]
    float* __restrict__ g_colsum,        // [64]  (zeroed by memset)
    unsigned int* __restrict__ g_cnt,    // [64]  (zeroed)
    float* __restrict__ g_nll,           // [1]   (zeroed)
    int n)
{
    __shared__ float s_col[NUM_CLASSES];
    __shared__ unsigned int s_cnt[NUM_CLASSES];
    __shared__ float s_nll[4];

    const int t = threadIdx.x;
    if (t < NUM_CLASSES) { s_col[t] = 0.f; s_cnt[t] = 0u; }
    __syncthreads();

    const int c16  = t & 15;          // column quad
    const int rloc = t >> 4;          // row slot within 16-row group
    const int c0   = c16 * 4;

    // balanced slab ranges: block b owns slabs [b*S/G, (b+1)*S/G) of 64 rows.
    // For n=2M, G=1250: exactly 25 full slabs per block, no tail, no masking.
    const long slabs = (n + 63) >> 6;
    const long s0 = (long)blockIdx.x * slabs / GRID;
    const long s1 = (long)(blockIdx.x + 1) * slabs / GRID;

    float ca0 = 0.f, ca1 = 0.f, ca2 = 0.f, ca3 = 0.f;
    float nllacc = 0.f;

    for (long s = s0; s < s1; ++s) {
        const long base = s << 6;
        if (base + 64 <= n) {           // full slab (always, when 64 | n)
            f32x4 v[4];
            int   tg[4];
            #pragma unroll
            for (int j = 0; j < 4; ++j) {   // issue all loads first (ILP)
                const long row = base + rloc + j * 16;
                v[j]  = __builtin_nontemporal_load(
                          reinterpret_cast<const f32x4*>(pred + row * NUM_CLASSES + c0));
                tg[j] = tgt[row];           // plain load: L1 broadcast x16 lanes
            }
            #pragma unroll
            for (int j = 0; j < 4; ++j) {
                ca0 += __expf(v[j][0]);
                ca1 += __expf(v[j][1]);
                ca2 += __expf(v[j][2]);
                ca3 += __expf(v[j][3]);
                if (c16 == j) atomicAdd(&s_cnt[tg[j]], 1u);  // spread hist atomics
                const int d = tg[j] - c0;
                if ((unsigned)d < 4u)
                    nllacc += (d==0)?v[j][0]:(d==1)?v[j][1]:(d==2)?v[j][2]:v[j][3];
            }
        } else {                        // masked last slab (n % 64 != 0 only)
            #pragma unroll
            for (int j = 0; j < 4; ++j) {
                const long row = base + rloc + j * 16;
                if (row < n) {
                    const f32x4 w = *reinterpret_cast<const f32x4*>(pred + row * NUM_CLASSES + c0);
                    const int g = tgt[row];
                    ca0 += __expf(w[0]); ca1 += __expf(w[1]);
                    ca2 += __expf(w[2]); ca3 += __expf(w[3]);
                    if (c16 == j) atomicAdd(&s_cnt[g], 1u);
                    const int d = g - c0;
                    if ((unsigned)d < 4u) nllacc += (d==0)?w[0]:(d==1)?w[1]:(d==2)?w[2]:w[3];
                }
            }
        }
    }

    // block reduction
    atomicAdd(&s_col[c0 + 0], ca0);
    atomicAdd(&s_col[c0 + 1], ca1);
    atomicAdd(&s_col[c0 + 2], ca2);
    atomicAdd(&s_col[c0 + 3], ca3);

    for (int off = 32; off; off >>= 1) nllacc += __shfl_down(nllacc, off);
    if ((t & 63) == 0) s_nll[t >> 6] = nllacc;
    __syncthreads();

    // device-scope atomic accumulation (66 atomics/block; R2-proven)
    if (t == 0) atomicAdd(g_nll, s_nll[0] + s_nll[1] + s_nll[2] + s_nll[3]);
    if (t < NUM_CLASSES) {
        atomicAdd(&g_colsum[t], s_col[t]);
        atomicAdd(&g_cnt[t], s_cnt[t]);
    }
}

// Finalize: 64 threads, reads 516B, writes the scalar.
__global__ void loss_finalize(const float* __restrict__ g_colsum,
                              const unsigned int* __restrict__ g_cnt,
                              const float* __restrict__ g_nll,
                              float* __restrict__ out, int n)
{
    const int t = threadIdx.x;
    const float diff = (float)g_cnt[t] - g_colsum[t];
    float p = diff * diff;
    for (int off = 32; off; off >>= 1) p += __shfl_down(p, off);
    if (t == 0) out[0] = (p - g_nll[0]) / (float)n;
}

extern "C" void kernel_launch(void* const* d_in, const int* in_sizes, int n_in,
                              void* d_out, int out_size, void* d_ws, size_t ws_size,
                              hipStream_t stream)
{
    const float* pred = (const float*)d_in[0];
    const int* tgt    = (const int*)d_in[1];
    const int n       = in_sizes[1];

    float*        g_colsum = (float*)d_ws;
    unsigned int* g_cnt    = (unsigned int*)((char*)d_ws + 256);
    float*        g_nll    = (float*)((char*)d_ws + 512);

    (void)hipMemsetAsync(d_ws, 0, 1024, stream);

    loss_pass1<<<GRID, 256, 0, stream>>>(pred, tgt, g_colsum, g_cnt, g_nll, n);
    loss_finalize<<<1, 64, 0, stream>>>(g_colsum, g_cnt, g_nll, (float*)d_out, n);
}